// Round 9
// baseline (503.666 us; speedup 1.0000x reference)
//
#include <hip/hip_runtime.h>
#include <hip/hip_bf16.h>
#include <stdint.h>

// ---------------------------------------------------------------------------
// SelfAttention QKV projection + head-indexed RoPE, MI355X (gfx950)
//   q = rope(x @ Wq), k = rope(x @ Wk), v = x @ Wv   (pos = head index!)
// Round 9: B-operand DIRECT FROM GLOBAL to registers (no LDS for B).
//   Cycle model said r8 was LDS-port + MFMA serialized (2600+2480 cyc/tile);
//   removing B from LDS cuts port time to ~1400 cyc -> MFMA-bound.
//   LDS: A only, 2x32KiB static. 1 barrier/tile, vmcnt(4) gate.
//   B loads time-share registers (loaded right after predecessor's death,
//   ~1200+ cyc before use). A-frag reads pipelined (counted lgkm).
// ---------------------------------------------------------------------------

typedef __attribute__((ext_vector_type(8))) short short8;
typedef __attribute__((ext_vector_type(4))) float f32x4;

__device__ __forceinline__ unsigned short f2bf(float f) {
  __bf16 h = (__bf16)f;
  return __builtin_bit_cast(unsigned short, h);
}

__device__ __forceinline__ void gload_lds16(const void* g, void* l) {
  __builtin_amdgcn_global_load_lds((const __attribute__((address_space(1))) void*)g,
                                   (__attribute__((address_space(3))) void*)l,
                                   16, 0, 0);
}

// ---------------- prep kernels ----------------

__global__ __launch_bounds__(256) void convert_x(const float* __restrict__ X,
                                                 unsigned short* __restrict__ Xb,
                                                 int n8) {
  const int stride = gridDim.x * blockDim.x;
  for (int i = blockIdx.x * blockDim.x + threadIdx.x; i < n8; i += stride) {
    const float4 v0 = ((const float4*)X)[(size_t)i * 2 + 0];
    const float4 v1 = ((const float4*)X)[(size_t)i * 2 + 1];
    uint4 w;
    w.x = (uint32_t)f2bf(v0.x) | ((uint32_t)f2bf(v0.y) << 16);
    w.y = (uint32_t)f2bf(v0.z) | ((uint32_t)f2bf(v0.w) << 16);
    w.z = (uint32_t)f2bf(v1.x) | ((uint32_t)f2bf(v1.y) << 16);
    w.w = (uint32_t)f2bf(v1.z) | ((uint32_t)f2bf(v1.w) << 16);
    ((uint4*)Xb)[i] = w;
  }
}

// W (2048x2048 f32, K x N) -> WT (bf16, N x K); z selects which W.
__global__ __launch_bounds__(256) void transpose_cvt3(const float* __restrict__ W0,
                                                      const float* __restrict__ W1,
                                                      const float* __restrict__ W2,
                                                      unsigned short* __restrict__ WT) {
  __shared__ unsigned short tile[64][65];
  const int z = blockIdx.z;
  const float* W = (z == 0) ? W0 : (z == 1) ? W1 : W2;
  unsigned short* WTz = WT + (size_t)z * 2048 * 2048;
  const int bx = blockIdx.x * 64;             // N origin
  const int by = blockIdx.y * 64;             // K origin
  const int t  = threadIdx.x;
  const int tr = t >> 4;
  const int tc = (t & 15) * 4;
#pragma unroll
  for (int i = 0; i < 4; ++i) {
    const int r = tr + i * 16;
    const float4 v = *(const float4*)&W[(size_t)(by + r) * 2048 + bx + tc];
    tile[r][tc + 0] = f2bf(v.x);
    tile[r][tc + 1] = f2bf(v.y);
    tile[r][tc + 2] = f2bf(v.z);
    tile[r][tc + 3] = f2bf(v.w);
  }
  __syncthreads();
#pragma unroll
  for (int i = 0; i < 4; ++i) {
    const int a = tr + i * 16;
    ushort4 o;
    o.x = tile[tc + 0][a];
    o.y = tile[tc + 1][a];
    o.z = tile[tc + 2][a];
    o.w = tile[tc + 3][a];
    *(ushort4*)&WTz[(size_t)(bx + a) * 2048 + by + tc] = o;
  }
}

// ---------------- fused 256x256 GEMM, BK=64, B-direct-from-global ----------
// LDS: A only: buf b at b*32KiB, A[256][64] bf16 (128B rows).
// A swizzle: 16B slot s_phys = s_log ^ (row&7); frag byte = s0 ^ (kk<<6).
// B frag (ni,ks) at tile kt: lane reads WT[(n0+wn+ni*16+l15)*2048+kt+ks*32+lg*8]
//   (16 contiguous B per lane; 16 rows x 64B segments per instruction).
// Pipeline per tile T: {load bc1(T) (used c2); stage A(T+1); a-frag reads
//   pipelined; c0,c1 use BCUR (loaded tile T-1); load BNXT (BC0(T+1)) after
//   BCUR's last use; c2,c3 use bc1; vmcnt(4) gate (drain A(T+1), keep BNXT
//   in flight); barrier}. 1 barrier/tile.

__global__ __launch_bounds__(512, 2) void qkv_fused14(const unsigned short* __restrict__ Xb,
                                                      const unsigned short* __restrict__ WT,
                                                      float* __restrict__ Out) {
  __shared__ char smemA[2][32768];

  // XCD-aware swizzle (1536 blocks, 1536 % 8 == 0 -> bijective)
  const int wg  = blockIdx.x;
  const int swz = (wg & 7) * 192 + (wg >> 3);
  const int mb  = swz / 24, nb = swz % 24;
  const int m0  = mb * 256, n0 = nb * 256;

  const int tid  = threadIdx.x;
  const int wave = tid >> 6, lane = tid & 63;
  const int l15  = lane & 15, lg = lane >> 4;
  const int wm   = (wave >> 2) * 128;          // 2 wave-rows
  const int wn   = (wave & 3) * 64;            // 4 wave-cols
  const int s0   = ((lg ^ (l15 & 7)) << 4);    // kk0 frag slot; kk1 = s0^64

  const unsigned short* Xp = Xb + (size_t)m0 * 2048;
  // per-lane B base: row = n0+wn+l15, k-offset = lg*8
  const unsigned short* Bp = WT + (size_t)(n0 + wn + l15) * 2048 + lg * 8;

  const int srow  = tid >> 3;                  // 0..63
  const int sslot = tid & 7;                   // physical 16B slot

  f32x4 acc[8][4] = {};

#define GLD_A(TP1)                                                            \
  do {                                                                        \
    char* dst_ = &smemA[0][0] + (((TP1) & 1) << 15);                          \
    _Pragma("unroll") for (int i_ = 0; i_ < 4; ++i_) {                        \
      const int row_ = i_ * 64 + srow;                                        \
      gload_lds16(Xp + (size_t)row_ * 2048 + (TP1) * 64 +                     \
                      ((sslot ^ (row_ & 7)) << 3),                            \
                  dst_ + i_ * 8192 + tid * 16);                               \
    }                                                                         \
  } while (0)

#define LDB4G(DST, KT, KS)                                                    \
  _Pragma("unroll") for (int ni_ = 0; ni_ < 4; ++ni_)                         \
      (DST)[ni_] = *(const short8*)(Bp + (size_t)ni_ * 32768 + (KT) +         \
                                    (KS) * 32);

#define LDA4(DST, MH, KS)                                                     \
  _Pragma("unroll") for (int mi_ = 0; mi_ < 4; ++mi_)                         \
      (DST)[mi_] = *(const short8*)(Ab +                                      \
          ((wm + (MH) * 64 + mi_ * 16 + l15) << 7) + (s0 ^ ((KS) << 6)));

#define MFMA16(MH, AR, BR)                                                    \
  do {                                                                        \
    __builtin_amdgcn_s_setprio(1);                                            \
    _Pragma("unroll") for (int mi_ = 0; mi_ < 4; ++mi_)                       \
      _Pragma("unroll") for (int ni_ = 0; ni_ < 4; ++ni_)                     \
        asm("v_mfma_f32_16x16x32_bf16 %0, %1, %2, %0"                         \
            : "+v"(acc[(MH) * 4 + mi_][ni_])                                  \
            : "v"((AR)[mi_]), "v"((BR)[ni_]));                                \
    __builtin_amdgcn_s_setprio(0);                                            \
  } while (0)

// Tile body. BCUR = B ks0 frags (loaded during tile T-1); BNXT gets BC0(T+1).
#define TILE(T, BCUR, BNXT, DO_STAGE)                                         \
  do {                                                                        \
    const char* Ab = &smemA[0][0] + (((T) & 1) << 15);                        \
    short8 a0[4], a1[4], bc1[4];                                              \
    LDB4G(bc1, (T) * 64, 1);          /* BC1(T), first use at c2 */           \
    if (DO_STAGE) GLD_A((T) + 1);                                             \
    LDA4(a0, 0, 0);                                                           \
    LDA4(a1, 1, 0);                                                           \
    MFMA16(0, a0, BCUR);              /* c0 */                                \
    LDA4(a0, 0, 1);                                                           \
    MFMA16(1, a1, BCUR);              /* c1 — BCUR dead after */              \
    if (DO_STAGE) LDB4G(BNXT, ((T) + 1) * 64, 0);                             \
    LDA4(a1, 1, 1);                                                           \
    MFMA16(0, a0, bc1);               /* c2 */                                \
    MFMA16(1, a1, bc1);               /* c3 */                                \
    if (DO_STAGE) {                                                           \
      asm volatile("s_waitcnt vmcnt(4)" ::: "memory");                        \
      __builtin_amdgcn_s_barrier();                                           \
    }                                                                         \
  } while (0)

  short8 bA[4], bB[4];

  // prologue: A(0), BC0(0); gate drains A(0), leaves bA's 4 loads in flight
  GLD_A(0);
  LDB4G(bA, 0, 0);
  asm volatile("s_waitcnt vmcnt(4)" ::: "memory");
  __builtin_amdgcn_s_barrier();

  for (int tt = 0; tt < 15; ++tt) {     // tiles 0..29
    TILE(2 * tt,     bA, bB, 1);
    TILE(2 * tt + 1, bB, bA, 1);
  }
  TILE(30, bA, bB, 1);                  // stages A(31), loads BC0(31)->bB
  TILE(31, bB, bA, 0);                  // no stage, no gate

#undef GLD_A
#undef LDB4G
#undef LDA4
#undef MFMA16
#undef TILE

  // epilogue: fused RoPE. C layout: col=lane&15, row=(lane>>4)*4+reg.
#pragma unroll
  for (int ni = 0; ni < 4; ++ni) {
    const int col = n0 + wn + ni * 16 + l15;
    const int sec = col >> 11;                 // 0=q,1=k,2=v
    const int lc  = col & 2047;
    float c = 1.0f, ssg = 0.0f;
    if (sec < 2) {
      const int h = lc >> 7;
      const int p = (lc & 127) >> 1;
      const float theta = exp2f(-(float)p * 0.20762050593046014f); // log2(1e4)/64
      float s;
      sincosf((float)h * theta, &s, &c);
      ssg = (l15 & 1) ? s : -s;
    }
    float* outp = Out + (size_t)sec * 33554432 + lc;
#pragma unroll
    for (int mi = 0; mi < 8; ++mi) {
      const f32x4 a = acc[mi][ni];
#pragma unroll
      for (int r = 0; r < 4; ++r) {
        const float val = a[r];
        float res = val;
        if (sec < 2) {
          const float other = __shfl_xor(val, 1);
          res = val * c + other * ssg;
        }
        __builtin_nontemporal_store(
            res, outp + (size_t)(m0 + wm + mi * 16 + lg * 4 + r) * 2048);
      }
    }
  }
}

// ---------------- fallback GEMM (ws too small) ----------------
__global__ __launch_bounds__(256) void qkv_gemm_small(const float* __restrict__ X,
                                                      const unsigned short* __restrict__ WTl,
                                                      float* __restrict__ Out,
                                                      const int do_rope) {
  __shared__ unsigned short As[128 * 64];
  __shared__ unsigned short Bs[128 * 64];
  const int t    = threadIdx.x;
  const int wave = t >> 6, lane = t & 63;
  const int l15  = lane & 15, lg = lane >> 4;
  const int wm   = (wave >> 1) * 64;
  const int wn   = (wave & 1) * 64;
  const int m0   = blockIdx.y * 128;
  const int n0   = blockIdx.x * 128;

  f32x4 acc[4][4] = {};

  for (int kt = 0; kt < 2048; kt += 64) {
#pragma unroll
    for (int i = 0; i < 8; ++i) {
      const int f = i * 256 + t;
      const int row = f >> 4, chunk = f & 15;
      const float4 v = *(const float4*)&X[(size_t)(m0 + row) * 2048 + kt + chunk * 4];
      const uint32_t lo = (uint32_t)f2bf(v.x) | ((uint32_t)f2bf(v.y) << 16);
      const uint32_t hi = (uint32_t)f2bf(v.z) | ((uint32_t)f2bf(v.w) << 16);
      const int slot = chunk >> 1;
      const int off  = row * 128 + (((slot ^ (row & 7)) << 4) | ((chunk & 1) << 3));
      uint2* p = (uint2*)((char*)As + off);
      p->x = lo; p->y = hi;
    }
#pragma unroll
    for (int i = 0; i < 4; ++i) {
      const int seg = i * 4 + wave;
      const int row = seg * 8 + (lane >> 3);
      const int ps  = lane & 7;
      const int ss  = ps ^ (row & 7);
      gload_lds16(WTl + (size_t)(n0 + row) * 2048 + kt + ss * 8,
                  (char*)Bs + seg * 1024 + lane * 16);
    }
    __syncthreads();
#pragma unroll
    for (int kk = 0; kk < 2; ++kk) {
      short8 afr[4], bfr[4];
#pragma unroll
      for (int mi = 0; mi < 4; ++mi) {
        const int row  = wm + mi * 16 + l15;
        const int slot = kk * 4 + lg;
        afr[mi] = *(const short8*)((const char*)As + row * 128 + ((slot ^ (row & 7)) << 4));
      }
#pragma unroll
      for (int ni = 0; ni < 4; ++ni) {
        const int row  = wn + ni * 16 + l15;
        const int slot = kk * 4 + lg;
        bfr[ni] = *(const short8*)((const char*)Bs + row * 128 + ((slot ^ (row & 7)) << 4));
      }
#pragma unroll
      for (int mi = 0; mi < 4; ++mi)
#pragma unroll
        for (int ni = 0; ni < 4; ++ni)
          asm("v_mfma_f32_16x16x32_bf16 %0, %1, %2, %0"
              : "+v"(acc[mi][ni])
              : "v"(afr[mi]), "v"(bfr[ni]));
    }
    __syncthreads();
  }

#pragma unroll
  for (int ni = 0; ni < 4; ++ni) {
    const int col = n0 + wn + ni * 16 + l15;
    float c = 1.0f, ssg = 0.0f;
    if (do_rope) {
      const int h = col >> 7;
      const int p = (col & 127) >> 1;
      const float theta = exp2f(-(float)p * 0.20762050593046014f);
      float s;
      sincosf((float)h * theta, &s, &c);
      ssg = (l15 & 1) ? s : -s;
    }
#pragma unroll
    for (int mi = 0; mi < 4; ++mi) {
      const f32x4 a = acc[mi][ni];
#pragma unroll
      for (int r = 0; r < 4; ++r) {
        const float val = a[r];
        float res = val;
        if (do_rope) {
          const float other = __shfl_xor(val, 1);
          res = val * c + other * ssg;
        }
        Out[(size_t)(m0 + wm + mi * 16 + lg * 4 + r) * 2048 + col] = res;
      }
    }
  }
}

extern "C" void kernel_launch(void* const* d_in, const int* in_sizes, int n_in,
                              void* d_out, int out_size, void* d_ws, size_t ws_size,
                              hipStream_t stream) {
  (void)in_sizes; (void)n_in; (void)out_size;
  const float* x  = (const float*)d_in[0];
  const float* Wq = (const float*)d_in[1];
  const float* Wk = (const float*)d_in[2];
  const float* Wv = (const float*)d_in[3];
  float* out = (float*)d_out;

  const size_t XB_ELEMS = 16384ull * 2048;
  const size_t WT_ELEMS = 6144ull * 2048;

  if (ws_size >= (XB_ELEMS + WT_ELEMS) * sizeof(unsigned short)) {
    unsigned short* Xb  = (unsigned short*)d_ws;
    unsigned short* WTf = Xb + XB_ELEMS;
    convert_x<<<2048, 256, 0, stream>>>(x, Xb, (int)(XB_ELEMS / 8));
    transpose_cvt3<<<dim3(32, 32, 3), 256, 0, stream>>>(Wq, Wk, Wv, WTf);
    qkv_fused14<<<1536, 512, 0, stream>>>(Xb, WTf, out);
  } else {
    unsigned short* WqT = (unsigned short*)d_ws;
    unsigned short* WkT = WqT + 2048ull * 2048;
    unsigned short* WvT = WkT + 2048ull * 2048;
    dim3 tb(256), tg(32, 32);
    transpose_cvt3<<<dim3(32, 32, 1), 256, 0, stream>>>(Wq, Wq, Wq, WqT);
    transpose_cvt3<<<dim3(32, 32, 1), 256, 0, stream>>>(Wk, Wk, Wk, WkT);
    transpose_cvt3<<<dim3(32, 32, 1), 256, 0, stream>>>(Wv, Wv, Wv, WvT);
    dim3 gg(16, 128);
    qkv_gemm_small<<<gg, tb, 0, stream>>>(x, WqT, out,            1);
    qkv_gemm_small<<<gg, tb, 0, stream>>>(x, WkT, out + 33554432, 1);
    qkv_gemm_small<<<gg, tb, 0, stream>>>(x, WvT, out + 67108864, 0);
  }
}

// Round 10
// 437.717 us; speedup vs baseline: 1.1507x; 1.1507x over previous
//
#include <hip/hip_runtime.h>
#include <hip/hip_bf16.h>
#include <stdint.h>

// ---------------------------------------------------------------------------
// SelfAttention QKV projection + head-indexed RoPE, MI355X (gfx950)
//   q = rope(x @ Wq), k = rope(x @ Wk), v = x @ Wv   (pos = head index!)
// Round 10: r8 body with the tile-top serialization removed. The
//   lgkmcnt(0)+barrier (WAR guard for GLD_B overwriting B region) moves
//   from tile-top to mid-tile, right before the GLD_B issues. MFMA c0
//   starts on compiler-counted lgkm waits; read bursts split (b1 after c0).
//   vmcnt ledger identical to r8: [A(t+1)x4][B(t+2)x4], gate vmcnt(4),
//   t=30 -> vmcnt(0), t=31 bare. B-direct (r9) and 32x32 (r6) reverted —
//   both were fill-coalescing regressions.
// ---------------------------------------------------------------------------

typedef __attribute__((ext_vector_type(8))) short short8;
typedef __attribute__((ext_vector_type(4))) float f32x4;

__device__ __forceinline__ unsigned short f2bf(float f) {
  __bf16 h = (__bf16)f;
  return __builtin_bit_cast(unsigned short, h);
}

__device__ __forceinline__ void gload_lds16(const void* g, void* l) {
  __builtin_amdgcn_global_load_lds((const __attribute__((address_space(1))) void*)g,
                                   (__attribute__((address_space(3))) void*)l,
                                   16, 0, 0);
}

// ---------------- prep kernels ----------------

__global__ __launch_bounds__(256) void convert_x(const float* __restrict__ X,
                                                 unsigned short* __restrict__ Xb,
                                                 int n8) {
  const int stride = gridDim.x * blockDim.x;
  for (int i = blockIdx.x * blockDim.x + threadIdx.x; i < n8; i += stride) {
    const float4 v0 = ((const float4*)X)[(size_t)i * 2 + 0];
    const float4 v1 = ((const float4*)X)[(size_t)i * 2 + 1];
    uint4 w;
    w.x = (uint32_t)f2bf(v0.x) | ((uint32_t)f2bf(v0.y) << 16);
    w.y = (uint32_t)f2bf(v0.z) | ((uint32_t)f2bf(v0.w) << 16);
    w.z = (uint32_t)f2bf(v1.x) | ((uint32_t)f2bf(v1.y) << 16);
    w.w = (uint32_t)f2bf(v1.z) | ((uint32_t)f2bf(v1.w) << 16);
    ((uint4*)Xb)[i] = w;
  }
}

// W (2048x2048 f32, K x N) -> WT (bf16, N x K); z selects which W.
__global__ __launch_bounds__(256) void transpose_cvt3(const float* __restrict__ W0,
                                                      const float* __restrict__ W1,
                                                      const float* __restrict__ W2,
                                                      unsigned short* __restrict__ WT) {
  __shared__ unsigned short tile[64][65];
  const int z = blockIdx.z;
  const float* W = (z == 0) ? W0 : (z == 1) ? W1 : W2;
  unsigned short* WTz = WT + (size_t)z * 2048 * 2048;
  const int bx = blockIdx.x * 64;             // N origin
  const int by = blockIdx.y * 64;             // K origin
  const int t  = threadIdx.x;
  const int tr = t >> 4;
  const int tc = (t & 15) * 4;
#pragma unroll
  for (int i = 0; i < 4; ++i) {
    const int r = tr + i * 16;
    const float4 v = *(const float4*)&W[(size_t)(by + r) * 2048 + bx + tc];
    tile[r][tc + 0] = f2bf(v.x);
    tile[r][tc + 1] = f2bf(v.y);
    tile[r][tc + 2] = f2bf(v.z);
    tile[r][tc + 3] = f2bf(v.w);
  }
  __syncthreads();
#pragma unroll
  for (int i = 0; i < 4; ++i) {
    const int a = tr + i * 16;
    ushort4 o;
    o.x = tile[tc + 0][a];
    o.y = tile[tc + 1][a];
    o.z = tile[tc + 2][a];
    o.w = tile[tc + 3][a];
    *(ushort4*)&WTz[(size_t)(bx + a) * 2048 + by + tc] = o;
  }
}

// ---------------- fused 256x256 GEMM, BK=64, drift pipeline v2 -------------
// LDS: buf b at b*64KiB: A[256][64] then B[256][64] (128B rows).
// Swizzle: 16B slot s_phys = s_log ^ (row&7); frag byte = s0 ^ (kk<<6).
// Tile body: GLD_A(t+1); read b0,a0,a1; MFMA c0 (counted lgkm waits);
//   read b1,a0'; MFMA c1; [lgkmcnt(0); barrier]  <- WAR guard, mid-tile;
//   GLD_B(t+2) x2; read a1'; MFMA c2; MFMA c3; vmcnt gate; barrier.
// WAR: GLD_B(t+2) overwrites current buffer's B region only after the
//   mid-barrier (own reads via lgkmcnt(0), all waves via barrier).
//   GLD_A(t+1) targets the other buffer whose reads finished before the
//   previous tile-end barrier (every read's consuming MFMA precedes it).
// RAW: gate vmcnt(4) leaves only B(t+2)'s 4 loads in flight => A(t+1) and
//   B(t+1) complete before any wave enters tile t+1. t=30 gate vmcnt(0)
//   (drains A(31)+B(31)); t=31 has no stage/gate.

__global__ __launch_bounds__(512, 2) void qkv_fused15(const unsigned short* __restrict__ Xb,
                                                      const unsigned short* __restrict__ WT,
                                                      float* __restrict__ Out) {
  extern __shared__ char smem[];

  // XCD-aware swizzle (1536 blocks, 1536 % 8 == 0 -> bijective)
  const int wg  = blockIdx.x;
  const int swz = (wg & 7) * 192 + (wg >> 3);
  const int mb  = swz / 24, nb = swz % 24;
  const int m0  = mb * 256, n0 = nb * 256;

  const int tid  = threadIdx.x;
  const int wave = tid >> 6, lane = tid & 63;
  const int l15  = lane & 15, lg = lane >> 4;
  const int wm   = (wave >> 2) * 128;          // 2 wave-rows
  const int wn   = (wave & 3) * 64;            // 4 wave-cols
  const int s0   = ((lg ^ (l15 & 7)) << 4);    // kk0 frag slot; kk1 = s0^64

  const unsigned short* Xp = Xb + (size_t)m0 * 2048;
  const unsigned short* Wp = WT + (size_t)n0 * 2048;

  const int srow  = tid >> 3;                  // 0..63
  const int sslot = tid & 7;                   // physical 16B slot

  f32x4 acc[8][4] = {};

#define GLD_A(TP1)                                                            \
  do {                                                                        \
    char* dst_ = smem + (((TP1) & 1) << 16);                                  \
    _Pragma("unroll") for (int i_ = 0; i_ < 4; ++i_) {                        \
      const int row_ = i_ * 64 + srow;                                        \
      gload_lds16(Xp + (size_t)row_ * 2048 + (TP1) * 64 +                     \
                      ((sslot ^ (row_ & 7)) << 3),                            \
                  dst_ + i_ * 8192 + tid * 16);                               \
    }                                                                         \
  } while (0)

#define GLD_B(TP2, H)                                                         \
  do {                                                                        \
    char* dst_ = smem + (((TP2) & 1) << 16) + 32768 + ((H) << 14);            \
    _Pragma("unroll") for (int i_ = 0; i_ < 2; ++i_) {                        \
      const int row_ = (H) * 128 + i_ * 64 + srow;                            \
      gload_lds16(Wp + (size_t)row_ * 2048 + (TP2) * 64 +                     \
                      ((sslot ^ (row_ & 7)) << 3),                            \
                  dst_ + i_ * 8192 + tid * 16);                               \
    }                                                                         \
  } while (0)

#define LDA4(DST, MH, KS)                                                     \
  _Pragma("unroll") for (int mi_ = 0; mi_ < 4; ++mi_)                         \
      (DST)[mi_] = *(const short8*)(Ab +                                      \
          ((wm + (MH) * 64 + mi_ * 16 + l15) << 7) + (s0 ^ ((KS) << 6)));

#define LDB4(DST, KS)                                                         \
  _Pragma("unroll") for (int ni_ = 0; ni_ < 4; ++ni_)                         \
      (DST)[ni_] = *(const short8*)(Bb +                                      \
          ((wn + ni_ * 16 + l15) << 7) + (s0 ^ ((KS) << 6)));

#define MFMA16(MH, AR, BR)                                                    \
  do {                                                                        \
    __builtin_amdgcn_s_setprio(1);                                            \
    _Pragma("unroll") for (int mi_ = 0; mi_ < 4; ++mi_)                       \
      _Pragma("unroll") for (int ni_ = 0; ni_ < 4; ++ni_)                     \
        asm("v_mfma_f32_16x16x32_bf16 %0, %1, %2, %0"                         \
            : "+v"(acc[(MH) * 4 + mi_][ni_])                                  \
            : "v"((AR)[mi_]), "v"((BR)[ni_]));                                \
    __builtin_amdgcn_s_setprio(0);                                            \
  } while (0)

  // prologue: A(0), B(0), B(1); gate leaves B(1)'s 4 loads in flight
  GLD_A(0);
  GLD_B(0, 0); GLD_B(0, 1);
  GLD_B(1, 0); GLD_B(1, 1);
  asm volatile("s_waitcnt vmcnt(4)" ::: "memory");
  __builtin_amdgcn_s_barrier();

  for (int t = 0; t < 32; ++t) {
    const char* Ab = smem + ((t & 1) << 16);
    const char* Bb = Ab + 32768;
    short8 a0[4], a1[4], b0[4], b1[4];

    // ----- tile top: stage A(t+1) first, then frags for c0/c1 -----
    if (t < 31) GLD_A(t + 1);
    LDB4(b0, 0);
    LDA4(a0, 0, 0);
    LDA4(a1, 1, 0);
    MFMA16(0, a0, b0);                 // c0 — compiler-counted lgkm waits
    // ----- prefetch c2/c3 frags under c1 -----
    LDB4(b1, 1);
    LDA4(a0, 0, 1);
    MFMA16(1, a1, b0);                 // c1 — b0 dead after
    // ----- mid-tile WAR guard: all waves' B reads done, then overwrite ---
    asm volatile("s_waitcnt lgkmcnt(0)" ::: "memory");
    __builtin_amdgcn_s_barrier();
    if (t < 30) { GLD_B(t + 2, 0); GLD_B(t + 2, 1); }
    LDA4(a1, 1, 1);
    MFMA16(0, a0, b1);                 // c2
    MFMA16(1, a1, b1);                 // c3
    // ----- tile-end gate + barrier -----
    if (t == 30)     asm volatile("s_waitcnt vmcnt(0)" ::: "memory");
    else if (t < 30) asm volatile("s_waitcnt vmcnt(4)" ::: "memory");
    if (t < 31) __builtin_amdgcn_s_barrier();
  }

#undef GLD_A
#undef GLD_B
#undef LDA4
#undef LDB4
#undef MFMA16

  // epilogue: fused RoPE. C layout: col=lane&15, row=(lane>>4)*4+reg.
#pragma unroll
  for (int ni = 0; ni < 4; ++ni) {
    const int col = n0 + wn + ni * 16 + l15;
    const int sec = col >> 11;                 // 0=q,1=k,2=v
    const int lc  = col & 2047;
    float c = 1.0f, ssg = 0.0f;
    if (sec < 2) {
      const int h = lc >> 7;
      const int p = (lc & 127) >> 1;
      const float theta = exp2f(-(float)p * 0.20762050593046014f); // log2(1e4)/64
      float s;
      sincosf((float)h * theta, &s, &c);
      ssg = (l15 & 1) ? s : -s;
    }
    float* outp = Out + (size_t)sec * 33554432 + lc;
#pragma unroll
    for (int mi = 0; mi < 8; ++mi) {
      const f32x4 a = acc[mi][ni];
#pragma unroll
      for (int r = 0; r < 4; ++r) {
        const float val = a[r];
        float res = val;
        if (sec < 2) {
          const float other = __shfl_xor(val, 1);
          res = val * c + other * ssg;
        }
        __builtin_nontemporal_store(
            res, outp + (size_t)(m0 + wm + mi * 16 + lg * 4 + r) * 2048);
      }
    }
  }
}

// ---------------- fallback GEMM (ws too small) ----------------
__global__ __launch_bounds__(256) void qkv_gemm_small(const float* __restrict__ X,
                                                      const unsigned short* __restrict__ WTl,
                                                      float* __restrict__ Out,
                                                      const int do_rope) {
  __shared__ unsigned short As[128 * 64];
  __shared__ unsigned short Bs[128 * 64];
  const int t    = threadIdx.x;
  const int wave = t >> 6, lane = t & 63;
  const int l15  = lane & 15, lg = lane >> 4;
  const int wm   = (wave >> 1) * 64;
  const int wn   = (wave & 1) * 64;
  const int m0   = blockIdx.y * 128;
  const int n0   = blockIdx.x * 128;

  f32x4 acc[4][4] = {};

  for (int kt = 0; kt < 2048; kt += 64) {
#pragma unroll
    for (int i = 0; i < 8; ++i) {
      const int f = i * 256 + t;
      const int row = f >> 4, chunk = f & 15;
      const float4 v = *(const float4*)&X[(size_t)(m0 + row) * 2048 + kt + chunk * 4];
      const uint32_t lo = (uint32_t)f2bf(v.x) | ((uint32_t)f2bf(v.y) << 16);
      const uint32_t hi = (uint32_t)f2bf(v.z) | ((uint32_t)f2bf(v.w) << 16);
      const int slot = chunk >> 1;
      const int off  = row * 128 + (((slot ^ (row & 7)) << 4) | ((chunk & 1) << 3));
      uint2* p = (uint2*)((char*)As + off);
      p->x = lo; p->y = hi;
    }
#pragma unroll
    for (int i = 0; i < 4; ++i) {
      const int seg = i * 4 + wave;
      const int row = seg * 8 + (lane >> 3);
      const int ps  = lane & 7;
      const int ss  = ps ^ (row & 7);
      gload_lds16(WTl + (size_t)(n0 + row) * 2048 + kt + ss * 8,
                  (char*)Bs + seg * 1024 + lane * 16);
    }
    __syncthreads();
#pragma unroll
    for (int kk = 0; kk < 2; ++kk) {
      short8 afr[4], bfr[4];
#pragma unroll
      for (int mi = 0; mi < 4; ++mi) {
        const int row  = wm + mi * 16 + l15;
        const int slot = kk * 4 + lg;
        afr[mi] = *(const short8*)((const char*)As + row * 128 + ((slot ^ (row & 7)) << 4));
      }
#pragma unroll
      for (int ni = 0; ni < 4; ++ni) {
        const int row  = wn + ni * 16 + l15;
        const int slot = kk * 4 + lg;
        bfr[ni] = *(const short8*)((const char*)Bs + row * 128 + ((slot ^ (row & 7)) << 4));
      }
#pragma unroll
      for (int mi = 0; mi < 4; ++mi)
#pragma unroll
        for (int ni = 0; ni < 4; ++ni)
          asm("v_mfma_f32_16x16x32_bf16 %0, %1, %2, %0"
              : "+v"(acc[mi][ni])
              : "v"(afr[mi]), "v"(bfr[ni]));
    }
    __syncthreads();
  }

#pragma unroll
  for (int ni = 0; ni < 4; ++ni) {
    const int col = n0 + wn + ni * 16 + l15;
    float c = 1.0f, ssg = 0.0f;
    if (do_rope) {
      const int h = col >> 7;
      const int p = (col & 127) >> 1;
      const float theta = exp2f(-(float)p * 0.20762050593046014f);
      float s;
      sincosf((float)h * theta, &s, &c);
      ssg = (l15 & 1) ? s : -s;
    }
#pragma unroll
    for (int mi = 0; mi < 4; ++mi) {
      const f32x4 a = acc[mi][ni];
#pragma unroll
      for (int r = 0; r < 4; ++r) {
        const float val = a[r];
        float res = val;
        if (do_rope) {
          const float other = __shfl_xor(val, 1);
          res = val * c + other * ssg;
        }
        Out[(size_t)(m0 + wm + mi * 16 + lg * 4 + r) * 2048 + col] = res;
      }
    }
  }
}

extern "C" void kernel_launch(void* const* d_in, const int* in_sizes, int n_in,
                              void* d_out, int out_size, void* d_ws, size_t ws_size,
                              hipStream_t stream) {
  (void)in_sizes; (void)n_in; (void)out_size;
  const float* x  = (const float*)d_in[0];
  const float* Wq = (const float*)d_in[1];
  const float* Wk = (const float*)d_in[2];
  const float* Wv = (const float*)d_in[3];
  float* out = (float*)d_out;

  const size_t XB_ELEMS = 16384ull * 2048;
  const size_t WT_ELEMS = 6144ull * 2048;

  if (ws_size >= (XB_ELEMS + WT_ELEMS) * sizeof(unsigned short)) {
    unsigned short* Xb  = (unsigned short*)d_ws;
    unsigned short* WTf = Xb + XB_ELEMS;
    convert_x<<<2048, 256, 0, stream>>>(x, Xb, (int)(XB_ELEMS / 8));
    transpose_cvt3<<<dim3(32, 32, 3), 256, 0, stream>>>(Wq, Wk, Wv, WTf);
    hipFuncSetAttribute((const void*)qkv_fused15,
                        hipFuncAttributeMaxDynamicSharedMemorySize, 131072);
    qkv_fused15<<<1536, 512, 131072, stream>>>(Xb, WTf, out);
  } else {
    unsigned short* WqT = (unsigned short*)d_ws;
    unsigned short* WkT = WqT + 2048ull * 2048;
    unsigned short* WvT = WkT + 2048ull * 2048;
    dim3 tb(256), tg(32, 32);
    transpose_cvt3<<<dim3(32, 32, 1), 256, 0, stream>>>(Wq, Wq, Wq, WqT);
    transpose_cvt3<<<dim3(32, 32, 1), 256, 0, stream>>>(Wk, Wk, Wk, WkT);
    transpose_cvt3<<<dim3(32, 32, 1), 256, 0, stream>>>(Wv, Wv, Wv, WvT);
    dim3 gg(16, 128);
    qkv_gemm_small<<<gg, tb, 0, stream>>>(x, WqT, out,            1);
    qkv_gemm_small<<<gg, tb, 0, stream>>>(x, WkT, out + 33554432, 1);
    qkv_gemm_small<<<gg, tb, 0, stream>>>(x, WvT, out + 67108864, 0);
  }
}

// Round 11
// 421.200 us; speedup vs baseline: 1.1958x; 1.0392x over previous
//
#include <hip/hip_runtime.h>
#include <hip/hip_bf16.h>
#include <stdint.h>

// ---------------------------------------------------------------------------
// SelfAttention QKV projection + head-indexed RoPE, MI355X (gfx950)
//   q = rope(x @ Wq), k = rope(x @ Wk), v = x @ Wv   (pos = head index!)
// Round 11: TLP instead of ILP. 256x256 tile, BK=64, but 16 waves (1024
//   threads, 4Mx4N, 64x64/wave) -> acc 64 VGPR, __launch_bounds__(1024,4)
//   -> 4 waves/SIMD so LDS port time hides under other waves' MFMA.
//   Sync skeleton = r10 (mid lgkmcnt(0)+barrier before GLD_B overwrite,
//   counted vmcnt(2) gate + barrier at tile end). Frag reads sequential
//   (no prefetch) to fit 128 regs; TLP covers ds latency.
// ---------------------------------------------------------------------------

typedef __attribute__((ext_vector_type(8))) short short8;
typedef __attribute__((ext_vector_type(4))) float f32x4;

__device__ __forceinline__ unsigned short f2bf(float f) {
  __bf16 h = (__bf16)f;
  return __builtin_bit_cast(unsigned short, h);
}

__device__ __forceinline__ void gload_lds16(const void* g, void* l) {
  __builtin_amdgcn_global_load_lds((const __attribute__((address_space(1))) void*)g,
                                   (__attribute__((address_space(3))) void*)l,
                                   16, 0, 0);
}

// ---------------- prep kernels ----------------

__global__ __launch_bounds__(256) void convert_x(const float* __restrict__ X,
                                                 unsigned short* __restrict__ Xb,
                                                 int n8) {
  const int stride = gridDim.x * blockDim.x;
  for (int i = blockIdx.x * blockDim.x + threadIdx.x; i < n8; i += stride) {
    const float4 v0 = ((const float4*)X)[(size_t)i * 2 + 0];
    const float4 v1 = ((const float4*)X)[(size_t)i * 2 + 1];
    uint4 w;
    w.x = (uint32_t)f2bf(v0.x) | ((uint32_t)f2bf(v0.y) << 16);
    w.y = (uint32_t)f2bf(v0.z) | ((uint32_t)f2bf(v0.w) << 16);
    w.z = (uint32_t)f2bf(v1.x) | ((uint32_t)f2bf(v1.y) << 16);
    w.w = (uint32_t)f2bf(v1.z) | ((uint32_t)f2bf(v1.w) << 16);
    ((uint4*)Xb)[i] = w;
  }
}

// W (2048x2048 f32, K x N) -> WT (bf16, N x K); z selects which W.
__global__ __launch_bounds__(256) void transpose_cvt3(const float* __restrict__ W0,
                                                      const float* __restrict__ W1,
                                                      const float* __restrict__ W2,
                                                      unsigned short* __restrict__ WT) {
  __shared__ unsigned short tile[64][65];
  const int z = blockIdx.z;
  const float* W = (z == 0) ? W0 : (z == 1) ? W1 : W2;
  unsigned short* WTz = WT + (size_t)z * 2048 * 2048;
  const int bx = blockIdx.x * 64;             // N origin
  const int by = blockIdx.y * 64;             // K origin
  const int t  = threadIdx.x;
  const int tr = t >> 4;
  const int tc = (t & 15) * 4;
#pragma unroll
  for (int i = 0; i < 4; ++i) {
    const int r = tr + i * 16;
    const float4 v = *(const float4*)&W[(size_t)(by + r) * 2048 + bx + tc];
    tile[r][tc + 0] = f2bf(v.x);
    tile[r][tc + 1] = f2bf(v.y);
    tile[r][tc + 2] = f2bf(v.z);
    tile[r][tc + 3] = f2bf(v.w);
  }
  __syncthreads();
#pragma unroll
  for (int i = 0; i < 4; ++i) {
    const int a = tr + i * 16;
    ushort4 o;
    o.x = tile[tc + 0][a];
    o.y = tile[tc + 1][a];
    o.z = tile[tc + 2][a];
    o.w = tile[tc + 3][a];
    *(ushort4*)&WTz[(size_t)(bx + a) * 2048 + by + tc] = o;
  }
}

// ---------------- fused 256x256 GEMM, BK=64, 16 waves, 4/SIMD --------------
// LDS: buf b at b*64KiB: A[256][64] then B[256][64] (128B rows).
// Swizzle: 16B slot s_phys = s_log ^ (row&7); frag byte = s0 ^ (kk<<6).
// Tile body: GLD_A(t+1)x2; read b0,a0; MFMA c0 (ks0, counted lgkm);
//   read b1,a1; [lgkmcnt(0); barrier]; GLD_B(t+2)x2; MFMA c1 (ks1);
//   gate vmcnt(2); barrier.
// WAR: all tile-t ds_reads precede mid-barrier => GLD_B(t+2) overwrite safe;
//   GLD_A(t+1) targets buffer whose reads ended before t-1's mid-barrier.
// RAW: gate vmcnt(2) leaves only B(t+2) in flight => A(t+1),B(t+1) landed.
// t=30 gate vmcnt(0); t=31 no stage/gate.

__global__ __launch_bounds__(1024, 4) void qkv_fused16(const unsigned short* __restrict__ Xb,
                                                       const unsigned short* __restrict__ WT,
                                                       float* __restrict__ Out) {
  extern __shared__ char smem[];

  // XCD-aware swizzle (1536 blocks, 1536 % 8 == 0 -> bijective)
  const int wg  = blockIdx.x;
  const int swz = (wg & 7) * 192 + (wg >> 3);
  const int mb  = swz / 24, nb = swz % 24;
  const int m0  = mb * 256, n0 = nb * 256;

  const int tid  = threadIdx.x;
  const int wave = tid >> 6, lane = tid & 63;
  const int l15  = lane & 15, lg = lane >> 4;
  const int wm   = (wave >> 2) * 64;           // 4 wave-rows
  const int wn   = (wave & 3) * 64;            // 4 wave-cols
  const int s0   = ((lg ^ (l15 & 7)) << 4);    // kk0 frag slot; kk1 = s0^64

  const unsigned short* Xp = Xb + (size_t)m0 * 2048;
  const unsigned short* Wp = WT + (size_t)n0 * 2048;

  const int srow  = tid >> 3;                  // 0..127
  const int sslot = tid & 7;                   // physical 16B slot

  f32x4 acc[4][4] = {};

#define GLD_A(TP1)                                                            \
  do {                                                                        \
    char* dst_ = smem + (((TP1) & 1) << 16);                                  \
    _Pragma("unroll") for (int i_ = 0; i_ < 2; ++i_) {                        \
      const int row_ = i_ * 128 + srow;                                       \
      gload_lds16(Xp + (size_t)row_ * 2048 + (TP1) * 64 +                     \
                      ((sslot ^ (row_ & 7)) << 3),                            \
                  dst_ + i_ * 16384 + tid * 16);                              \
    }                                                                         \
  } while (0)

#define GLD_B(TP2)                                                            \
  do {                                                                        \
    char* dst_ = smem + (((TP2) & 1) << 16) + 32768;                          \
    _Pragma("unroll") for (int i_ = 0; i_ < 2; ++i_) {                        \
      const int row_ = i_ * 128 + srow;                                       \
      gload_lds16(Wp + (size_t)row_ * 2048 + (TP2) * 64 +                     \
                      ((sslot ^ (row_ & 7)) << 3),                            \
                  dst_ + i_ * 16384 + tid * 16);                              \
    }                                                                         \
  } while (0)

#define LDA4(DST, KS)                                                         \
  _Pragma("unroll") for (int mi_ = 0; mi_ < 4; ++mi_)                         \
      (DST)[mi_] = *(const short8*)(Ab +                                      \
          ((wm + mi_ * 16 + l15) << 7) + (s0 ^ ((KS) << 6)));

#define LDB4(DST, KS)                                                         \
  _Pragma("unroll") for (int ni_ = 0; ni_ < 4; ++ni_)                         \
      (DST)[ni_] = *(const short8*)(Bb +                                      \
          ((wn + ni_ * 16 + l15) << 7) + (s0 ^ ((KS) << 6)));

#define MFMA16(AR, BR)                                                        \
  do {                                                                        \
    __builtin_amdgcn_s_setprio(1);                                            \
    _Pragma("unroll") for (int mi_ = 0; mi_ < 4; ++mi_)                       \
      _Pragma("unroll") for (int ni_ = 0; ni_ < 4; ++ni_)                     \
        asm("v_mfma_f32_16x16x32_bf16 %0, %1, %2, %0"                         \
            : "+v"(acc[mi_][ni_])                                             \
            : "v"((AR)[mi_]), "v"((BR)[ni_]));                                \
    __builtin_amdgcn_s_setprio(0);                                            \
  } while (0)

  // prologue: A(0), B(0), B(1); gate leaves B(1)'s 2 loads in flight
  GLD_A(0);
  GLD_B(0);
  GLD_B(1);
  asm volatile("s_waitcnt vmcnt(2)" ::: "memory");
  __builtin_amdgcn_s_barrier();

  for (int t = 0; t < 32; ++t) {
    const char* Ab = smem + ((t & 1) << 16);
    const char* Bb = Ab + 32768;
    short8 a0[4], b0[4], a1[4], b1[4];

    // ----- tile top: stage A(t+1), then ks0 frags + MFMA -----
    if (t < 31) GLD_A(t + 1);
    LDB4(b0, 0);
    LDA4(a0, 0);
    MFMA16(a0, b0);                    // c0 — compiler-counted lgkm waits
    // ----- ks1 frags, then WAR guard, then B(t+2) overwrite -----
    LDB4(b1, 1);
    LDA4(a1, 1);
    asm volatile("s_waitcnt lgkmcnt(0)" ::: "memory");
    __builtin_amdgcn_s_barrier();
    if (t < 30) GLD_B(t + 2);
    MFMA16(a1, b1);                    // c1
    // ----- tile-end gate + barrier -----
    if (t == 30)     asm volatile("s_waitcnt vmcnt(0)" ::: "memory");
    else if (t < 30) asm volatile("s_waitcnt vmcnt(2)" ::: "memory");
    if (t < 31) __builtin_amdgcn_s_barrier();
  }

#undef GLD_A
#undef GLD_B
#undef LDA4
#undef LDB4
#undef MFMA16

  // epilogue: fused RoPE. C layout: col=lane&15, row=(lane>>4)*4+reg.
#pragma unroll
  for (int ni = 0; ni < 4; ++ni) {
    const int col = n0 + wn + ni * 16 + l15;
    const int sec = col >> 11;                 // 0=q,1=k,2=v
    const int lc  = col & 2047;
    float c = 1.0f, ssg = 0.0f;
    if (sec < 2) {
      const int h = lc >> 7;
      const int p = (lc & 127) >> 1;
      const float theta = exp2f(-(float)p * 0.20762050593046014f); // log2(1e4)/64
      float s;
      sincosf((float)h * theta, &s, &c);
      ssg = (l15 & 1) ? s : -s;
    }
    float* outp = Out + (size_t)sec * 33554432 + lc;
#pragma unroll
    for (int mi = 0; mi < 4; ++mi) {
      const f32x4 a = acc[mi][ni];
#pragma unroll
      for (int r = 0; r < 4; ++r) {
        const float val = a[r];
        float res = val;
        if (sec < 2) {
          const float other = __shfl_xor(val, 1);
          res = val * c + other * ssg;
        }
        __builtin_nontemporal_store(
            res, outp + (size_t)(m0 + wm + mi * 16 + lg * 4 + r) * 2048);
      }
    }
  }
}

// ---------------- fallback GEMM (ws too small) ----------------
__global__ __launch_bounds__(256) void qkv_gemm_small(const float* __restrict__ X,
                                                      const unsigned short* __restrict__ WTl,
                                                      float* __restrict__ Out,
                                                      const int do_rope) {
  __shared__ unsigned short As[128 * 64];
  __shared__ unsigned short Bs[128 * 64];
  const int t    = threadIdx.x;
  const int wave = t >> 6, lane = t & 63;
  const int l15  = lane & 15, lg = lane >> 4;
  const int wm   = (wave >> 1) * 64;
  const int wn   = (wave & 1) * 64;
  const int m0   = blockIdx.y * 128;
  const int n0   = blockIdx.x * 128;

  f32x4 acc[4][4] = {};

  for (int kt = 0; kt < 2048; kt += 64) {
#pragma unroll
    for (int i = 0; i < 8; ++i) {
      const int f = i * 256 + t;
      const int row = f >> 4, chunk = f & 15;
      const float4 v = *(const float4*)&X[(size_t)(m0 + row) * 2048 + kt + chunk * 4];
      const uint32_t lo = (uint32_t)f2bf(v.x) | ((uint32_t)f2bf(v.y) << 16);
      const uint32_t hi = (uint32_t)f2bf(v.z) | ((uint32_t)f2bf(v.w) << 16);
      const int slot = chunk >> 1;
      const int off  = row * 128 + (((slot ^ (row & 7)) << 4) | ((chunk & 1) << 3));
      uint2* p = (uint2*)((char*)As + off);
      p->x = lo; p->y = hi;
    }
#pragma unroll
    for (int i = 0; i < 4; ++i) {
      const int seg = i * 4 + wave;
      const int row = seg * 8 + (lane >> 3);
      const int ps  = lane & 7;
      const int ss  = ps ^ (row & 7);
      gload_lds16(WTl + (size_t)(n0 + row) * 2048 + kt + ss * 8,
                  (char*)Bs + seg * 1024 + lane * 16);
    }
    __syncthreads();
#pragma unroll
    for (int kk = 0; kk < 2; ++kk) {
      short8 afr[4], bfr[4];
#pragma unroll
      for (int mi = 0; mi < 4; ++mi) {
        const int row  = wm + mi * 16 + l15;
        const int slot = kk * 4 + lg;
        afr[mi] = *(const short8*)((const char*)As + row * 128 + ((slot ^ (row & 7)) << 4));
      }
#pragma unroll
      for (int ni = 0; ni < 4; ++ni) {
        const int row  = wn + ni * 16 + l15;
        const int slot = kk * 4 + lg;
        bfr[ni] = *(const short8*)((const char*)Bs + row * 128 + ((slot ^ (row & 7)) << 4));
      }
#pragma unroll
      for (int mi = 0; mi < 4; ++mi)
#pragma unroll
        for (int ni = 0; ni < 4; ++ni)
          asm("v_mfma_f32_16x16x32_bf16 %0, %1, %2, %0"
              : "+v"(acc[mi][ni])
              : "v"(afr[mi]), "v"(bfr[ni]));
    }
    __syncthreads();
  }

#pragma unroll
  for (int ni = 0; ni < 4; ++ni) {
    const int col = n0 + wn + ni * 16 + l15;
    float c = 1.0f, ssg = 0.0f;
    if (do_rope) {
      const int h = col >> 7;
      const int p = (col & 127) >> 1;
      const float theta = exp2f(-(float)p * 0.20762050593046014f);
      float s;
      sincosf((float)h * theta, &s, &c);
      ssg = (l15 & 1) ? s : -s;
    }
#pragma unroll
    for (int mi = 0; mi < 4; ++mi) {
      const f32x4 a = acc[mi][ni];
#pragma unroll
      for (int r = 0; r < 4; ++r) {
        const float val = a[r];
        float res = val;
        if (do_rope) {
          const float other = __shfl_xor(val, 1);
          res = val * c + other * ssg;
        }
        Out[(size_t)(m0 + wm + mi * 16 + lg * 4 + r) * 2048 + col] = res;
      }
    }
  }
}

extern "C" void kernel_launch(void* const* d_in, const int* in_sizes, int n_in,
                              void* d_out, int out_size, void* d_ws, size_t ws_size,
                              hipStream_t stream) {
  (void)in_sizes; (void)n_in; (void)out_size;
  const float* x  = (const float*)d_in[0];
  const float* Wq = (const float*)d_in[1];
  const float* Wk = (const float*)d_in[2];
  const float* Wv = (const float*)d_in[3];
  float* out = (float*)d_out;

  const size_t XB_ELEMS = 16384ull * 2048;
  const size_t WT_ELEMS = 6144ull * 2048;

  if (ws_size >= (XB_ELEMS + WT_ELEMS) * sizeof(unsigned short)) {
    unsigned short* Xb  = (unsigned short*)d_ws;
    unsigned short* WTf = Xb + XB_ELEMS;
    convert_x<<<2048, 256, 0, stream>>>(x, Xb, (int)(XB_ELEMS / 8));
    transpose_cvt3<<<dim3(32, 32, 3), 256, 0, stream>>>(Wq, Wk, Wv, WTf);
    hipFuncSetAttribute((const void*)qkv_fused16,
                        hipFuncAttributeMaxDynamicSharedMemorySize, 131072);
    qkv_fused16<<<1536, 1024, 131072, stream>>>(Xb, WTf, out);
  } else {
    unsigned short* WqT = (unsigned short*)d_ws;
    unsigned short* WkT = WqT + 2048ull * 2048;
    unsigned short* WvT = WkT + 2048ull * 2048;
    dim3 tb(256), tg(32, 32);
    transpose_cvt3<<<dim3(32, 32, 1), 256, 0, stream>>>(Wq, Wq, Wq, WqT);
    transpose_cvt3<<<dim3(32, 32, 1), 256, 0, stream>>>(Wk, Wk, Wk, WkT);
    transpose_cvt3<<<dim3(32, 32, 1), 256, 0, stream>>>(Wv, Wv, Wv, WvT);
    dim3 gg(16, 128);
    qkv_gemm_small<<<gg, tb, 0, stream>>>(x, WqT, out,            1);
    qkv_gemm_small<<<gg, tb, 0, stream>>>(x, WkT, out + 33554432, 1);
    qkv_gemm_small<<<gg, tb, 0, stream>>>(x, WvT, out + 67108864, 0);
  }
}

// Round 12
// 414.118 us; speedup vs baseline: 1.2162x; 1.0171x over previous
//
#include <hip/hip_runtime.h>
#include <hip/hip_bf16.h>
#include <stdint.h>

// ---------------------------------------------------------------------------
// SelfAttention QKV projection + head-indexed RoPE, MI355X (gfx950)
//   q = rope(x @ Wq), k = rope(x @ Wk), v = x @ Wv   (pos = head index!)
// Round 12: r11 (16 waves, 4/SIMD) + TRIPLE-BUFFERED B (160 KB LDS total)
//   -> the mid-tile lgkmcnt(0)+barrier is deleted; one counted vmcnt(2)
//   gate + one barrier per K-tile. GLD_B(t+2) writes buf (t+2)%3, never a
//   buffer being read; writes to buf t%3 (for B(t+3)) are issued only
//   after barrier t, and all reads of it complete before barrier t.
// ---------------------------------------------------------------------------

typedef __attribute__((ext_vector_type(8))) short short8;
typedef __attribute__((ext_vector_type(4))) float f32x4;

__device__ __forceinline__ unsigned short f2bf(float f) {
  __bf16 h = (__bf16)f;
  return __builtin_bit_cast(unsigned short, h);
}

__device__ __forceinline__ void gload_lds16(const void* g, void* l) {
  __builtin_amdgcn_global_load_lds((const __attribute__((address_space(1))) void*)g,
                                   (__attribute__((address_space(3))) void*)l,
                                   16, 0, 0);
}

// ---------------- prep kernels ----------------

__global__ __launch_bounds__(256) void convert_x(const float* __restrict__ X,
                                                 unsigned short* __restrict__ Xb,
                                                 int n8) {
  const int stride = gridDim.x * blockDim.x;
  for (int i = blockIdx.x * blockDim.x + threadIdx.x; i < n8; i += stride) {
    const float4 v0 = ((const float4*)X)[(size_t)i * 2 + 0];
    const float4 v1 = ((const float4*)X)[(size_t)i * 2 + 1];
    uint4 w;
    w.x = (uint32_t)f2bf(v0.x) | ((uint32_t)f2bf(v0.y) << 16);
    w.y = (uint32_t)f2bf(v0.z) | ((uint32_t)f2bf(v0.w) << 16);
    w.z = (uint32_t)f2bf(v1.x) | ((uint32_t)f2bf(v1.y) << 16);
    w.w = (uint32_t)f2bf(v1.z) | ((uint32_t)f2bf(v1.w) << 16);
    ((uint4*)Xb)[i] = w;
  }
}

// W (2048x2048 f32, K x N) -> WT (bf16, N x K); z selects which W.
__global__ __launch_bounds__(256) void transpose_cvt3(const float* __restrict__ W0,
                                                      const float* __restrict__ W1,
                                                      const float* __restrict__ W2,
                                                      unsigned short* __restrict__ WT) {
  __shared__ unsigned short tile[64][65];
  const int z = blockIdx.z;
  const float* W = (z == 0) ? W0 : (z == 1) ? W1 : W2;
  unsigned short* WTz = WT + (size_t)z * 2048 * 2048;
  const int bx = blockIdx.x * 64;             // N origin
  const int by = blockIdx.y * 64;             // K origin
  const int t  = threadIdx.x;
  const int tr = t >> 4;
  const int tc = (t & 15) * 4;
#pragma unroll
  for (int i = 0; i < 4; ++i) {
    const int r = tr + i * 16;
    const float4 v = *(const float4*)&W[(size_t)(by + r) * 2048 + bx + tc];
    tile[r][tc + 0] = f2bf(v.x);
    tile[r][tc + 1] = f2bf(v.y);
    tile[r][tc + 2] = f2bf(v.z);
    tile[r][tc + 3] = f2bf(v.w);
  }
  __syncthreads();
#pragma unroll
  for (int i = 0; i < 4; ++i) {
    const int a = tr + i * 16;
    ushort4 o;
    o.x = tile[tc + 0][a];
    o.y = tile[tc + 1][a];
    o.z = tile[tc + 2][a];
    o.w = tile[tc + 3][a];
    *(ushort4*)&WTz[(size_t)(bx + a) * 2048 + by + tc] = o;
  }
}

// ---------------- fused 256x256 GEMM, BK=64, 16 waves, B tri-buffer --------
// LDS (160 KB): A bufs at 0, 32768 (t&1); B bufs at 65536 + (t%3)*32768.
// Swizzle: 16B slot s_phys = s_log ^ (row&7); frag byte = s0 ^ (kk<<6).
// Tile body: GLD_A(t+1); read b0,a0; MFMA c0; GLD_B(t+2)->buf (t+2)%3;
//   read b1,a1; MFMA c1; gate vmcnt(2); barrier.   (NO mid-tile sync)
// WAR: writer of B buf t%3 is B(t+3), issued after barrier t; all reads of
//   it complete before barrier t (MFMA operand dependency). A(t+1) targets
//   buf read in t-1, finished before barrier t-1.
// RAW: gate queue = B(t+1)x2, A(t+1)x2, B(t+2)x2 -> vmcnt(2) drains
//   A(t+1)+B(t+1), keeps B(t+2). Prologue A(0),B(0),B(1)+vmcnt(2) matches.
//   t=30 gate vmcnt(0); t=31 no stage/gate.

__global__ __launch_bounds__(1024, 4) void qkv_fused17(const unsigned short* __restrict__ Xb,
                                                       const unsigned short* __restrict__ WT,
                                                       float* __restrict__ Out) {
  extern __shared__ char smem[];

  // XCD-aware swizzle (1536 blocks, 1536 % 8 == 0 -> bijective)
  const int wg  = blockIdx.x;
  const int swz = (wg & 7) * 192 + (wg >> 3);
  const int mb  = swz / 24, nb = swz % 24;
  const int m0  = mb * 256, n0 = nb * 256;

  const int tid  = threadIdx.x;
  const int wave = tid >> 6, lane = tid & 63;
  const int l15  = lane & 15, lg = lane >> 4;
  const int wm   = (wave >> 2) * 64;           // 4 wave-rows
  const int wn   = (wave & 3) * 64;            // 4 wave-cols
  const int s0   = ((lg ^ (l15 & 7)) << 4);    // kk0 frag slot; kk1 = s0^64

  const unsigned short* Xp = Xb + (size_t)m0 * 2048;
  const unsigned short* Wp = WT + (size_t)n0 * 2048;

  const int srow  = tid >> 3;                  // 0..127
  const int sslot = tid & 7;                   // physical 16B slot

  f32x4 acc[4][4] = {};

#define GLD_A(TP1)                                                            \
  do {                                                                        \
    char* dst_ = smem + (((TP1) & 1) << 15);                                  \
    _Pragma("unroll") for (int i_ = 0; i_ < 2; ++i_) {                        \
      const int row_ = i_ * 128 + srow;                                       \
      gload_lds16(Xp + (size_t)row_ * 2048 + (TP1) * 64 +                     \
                      ((sslot ^ (row_ & 7)) << 3),                            \
                  dst_ + i_ * 16384 + tid * 16);                              \
    }                                                                         \
  } while (0)

#define GLD_B(TP2, BUFI)                                                      \
  do {                                                                        \
    char* dst_ = smem + 65536 + (BUFI) * 32768;                               \
    _Pragma("unroll") for (int i_ = 0; i_ < 2; ++i_) {                        \
      const int row_ = i_ * 128 + srow;                                       \
      gload_lds16(Wp + (size_t)row_ * 2048 + (TP2) * 64 +                     \
                      ((sslot ^ (row_ & 7)) << 3),                            \
                  dst_ + i_ * 16384 + tid * 16);                              \
    }                                                                         \
  } while (0)

#define LDA4(DST, KS)                                                         \
  _Pragma("unroll") for (int mi_ = 0; mi_ < 4; ++mi_)                         \
      (DST)[mi_] = *(const short8*)(Ab +                                      \
          ((wm + mi_ * 16 + l15) << 7) + (s0 ^ ((KS) << 6)));

#define LDB4(DST, KS)                                                         \
  _Pragma("unroll") for (int ni_ = 0; ni_ < 4; ++ni_)                         \
      (DST)[ni_] = *(const short8*)(Bb +                                      \
          ((wn + ni_ * 16 + l15) << 7) + (s0 ^ ((KS) << 6)));

#define MFMA16(AR, BR)                                                        \
  do {                                                                        \
    __builtin_amdgcn_s_setprio(1);                                            \
    _Pragma("unroll") for (int mi_ = 0; mi_ < 4; ++mi_)                       \
      _Pragma("unroll") for (int ni_ = 0; ni_ < 4; ++ni_)                     \
        asm("v_mfma_f32_16x16x32_bf16 %0, %1, %2, %0"                         \
            : "+v"(acc[mi_][ni_])                                             \
            : "v"((AR)[mi_]), "v"((BR)[ni_]));                                \
    __builtin_amdgcn_s_setprio(0);                                            \
  } while (0)

  // prologue: A(0)->buf0, B(0)->buf0, B(1)->buf1; gate leaves B(1) in flight
  GLD_A(0);
  GLD_B(0, 0);
  GLD_B(1, 1);
  asm volatile("s_waitcnt vmcnt(2)" ::: "memory");
  __builtin_amdgcn_s_barrier();

  int bc = 0;                                  // B buffer index for tile t
  for (int t = 0; t < 32; ++t) {
    const char* Ab = smem + ((t & 1) << 15);
    const char* Bb = smem + 65536 + bc * 32768;
    const int bn2 = (bc == 0) ? 2 : bc - 1;    // (bc+2)%3
    short8 a0[4], b0[4], a1[4], b1[4];

    if (t < 31) GLD_A(t + 1);
    LDB4(b0, 0);
    LDA4(a0, 0);
    MFMA16(a0, b0);                    // c0 — compiler-counted lgkm waits
    if (t < 30) GLD_B(t + 2, bn2);     // never a buffer being read
    LDB4(b1, 1);
    LDA4(a1, 1);
    MFMA16(a1, b1);                    // c1
    if (t == 30)     asm volatile("s_waitcnt vmcnt(0)" ::: "memory");
    else if (t < 30) asm volatile("s_waitcnt vmcnt(2)" ::: "memory");
    if (t < 31) __builtin_amdgcn_s_barrier();
    bc = (bc == 2) ? 0 : bc + 1;
  }

#undef GLD_A
#undef GLD_B
#undef LDA4
#undef LDB4
#undef MFMA16

  // epilogue: fused RoPE. C layout: col=lane&15, row=(lane>>4)*4+reg.
#pragma unroll
  for (int ni = 0; ni < 4; ++ni) {
    const int col = n0 + wn + ni * 16 + l15;
    const int sec = col >> 11;                 // 0=q,1=k,2=v
    const int lc  = col & 2047;
    float c = 1.0f, ssg = 0.0f;
    if (sec < 2) {
      const int h = lc >> 7;
      const int p = (lc & 127) >> 1;
      const float theta = exp2f(-(float)p * 0.20762050593046014f); // log2(1e4)/64
      float s;
      sincosf((float)h * theta, &s, &c);
      ssg = (l15 & 1) ? s : -s;
    }
    float* outp = Out + (size_t)sec * 33554432 + lc;
#pragma unroll
    for (int mi = 0; mi < 4; ++mi) {
      const f32x4 a = acc[mi][ni];
#pragma unroll
      for (int r = 0; r < 4; ++r) {
        const float val = a[r];
        float res = val;
        if (sec < 2) {
          const float other = __shfl_xor(val, 1);
          res = val * c + other * ssg;
        }
        __builtin_nontemporal_store(
            res, outp + (size_t)(m0 + wm + mi * 16 + lg * 4 + r) * 2048);
      }
    }
  }
}

// ---------------- r11 kernel kept as fallback (128 KB LDS) ----------------
__global__ __launch_bounds__(1024, 4) void qkv_fused16(const unsigned short* __restrict__ Xb,
                                                       const unsigned short* __restrict__ WT,
                                                       float* __restrict__ Out) {
  extern __shared__ char smem[];
  const int wg  = blockIdx.x;
  const int swz = (wg & 7) * 192 + (wg >> 3);
  const int mb  = swz / 24, nb = swz % 24;
  const int m0  = mb * 256, n0 = nb * 256;

  const int tid  = threadIdx.x;
  const int wave = tid >> 6, lane = tid & 63;
  const int l15  = lane & 15, lg = lane >> 4;
  const int wm   = (wave >> 2) * 64;
  const int wn   = (wave & 3) * 64;
  const int s0   = ((lg ^ (l15 & 7)) << 4);

  const unsigned short* Xp = Xb + (size_t)m0 * 2048;
  const unsigned short* Wp = WT + (size_t)n0 * 2048;

  const int srow  = tid >> 3;
  const int sslot = tid & 7;

  f32x4 acc[4][4] = {};

#define GLD_A(TP1)                                                            \
  do {                                                                        \
    char* dst_ = smem + (((TP1) & 1) << 16);                                  \
    _Pragma("unroll") for (int i_ = 0; i_ < 2; ++i_) {                        \
      const int row_ = i_ * 128 + srow;                                       \
      gload_lds16(Xp + (size_t)row_ * 2048 + (TP1) * 64 +                     \
                      ((sslot ^ (row_ & 7)) << 3),                            \
                  dst_ + i_ * 16384 + tid * 16);                              \
    }                                                                         \
  } while (0)

#define GLD_B(TP2)                                                            \
  do {                                                                        \
    char* dst_ = smem + (((TP2) & 1) << 16) + 32768;                          \
    _Pragma("unroll") for (int i_ = 0; i_ < 2; ++i_) {                        \
      const int row_ = i_ * 128 + srow;                                       \
      gload_lds16(Wp + (size_t)row_ * 2048 + (TP2) * 64 +                     \
                      ((sslot ^ (row_ & 7)) << 3),                            \
                  dst_ + i_ * 16384 + tid * 16);                              \
    }                                                                         \
  } while (0)

#define LDA4(DST, KS)                                                         \
  _Pragma("unroll") for (int mi_ = 0; mi_ < 4; ++mi_)                         \
      (DST)[mi_] = *(const short8*)(Ab +                                      \
          ((wm + mi_ * 16 + l15) << 7) + (s0 ^ ((KS) << 6)));

#define LDB4(DST, KS)                                                         \
  _Pragma("unroll") for (int ni_ = 0; ni_ < 4; ++ni_)                         \
      (DST)[ni_] = *(const short8*)(Bb +                                      \
          ((wn + ni_ * 16 + l15) << 7) + (s0 ^ ((KS) << 6)));

#define MFMA16(AR, BR)                                                        \
  do {                                                                        \
    __builtin_amdgcn_s_setprio(1);                                            \
    _Pragma("unroll") for (int mi_ = 0; mi_ < 4; ++mi_)                       \
      _Pragma("unroll") for (int ni_ = 0; ni_ < 4; ++ni_)                     \
        asm("v_mfma_f32_16x16x32_bf16 %0, %1, %2, %0"                         \
            : "+v"(acc[mi_][ni_])                                             \
            : "v"((AR)[mi_]), "v"((BR)[ni_]));                                \
    __builtin_amdgcn_s_setprio(0);                                            \
  } while (0)

  GLD_A(0);
  GLD_B(0);
  GLD_B(1);
  asm volatile("s_waitcnt vmcnt(2)" ::: "memory");
  __builtin_amdgcn_s_barrier();

  for (int t = 0; t < 32; ++t) {
    const char* Ab = smem + ((t & 1) << 16);
    const char* Bb = Ab + 32768;
    short8 a0[4], b0[4], a1[4], b1[4];

    if (t < 31) GLD_A(t + 1);
    LDB4(b0, 0);
    LDA4(a0, 0);
    MFMA16(a0, b0);
    LDB4(b1, 1);
    LDA4(a1, 1);
    asm volatile("s_waitcnt lgkmcnt(0)" ::: "memory");
    __builtin_amdgcn_s_barrier();
    if (t < 30) GLD_B(t + 2);
    MFMA16(a1, b1);
    if (t == 30)     asm volatile("s_waitcnt vmcnt(0)" ::: "memory");
    else if (t < 30) asm volatile("s_waitcnt vmcnt(2)" ::: "memory");
    if (t < 31) __builtin_amdgcn_s_barrier();
  }

#undef GLD_A
#undef GLD_B
#undef LDA4
#undef LDB4
#undef MFMA16

#pragma unroll
  for (int ni = 0; ni < 4; ++ni) {
    const int col = n0 + wn + ni * 16 + l15;
    const int sec = col >> 11;
    const int lc  = col & 2047;
    float c = 1.0f, ssg = 0.0f;
    if (sec < 2) {
      const int h = lc >> 7;
      const int p = (lc & 127) >> 1;
      const float theta = exp2f(-(float)p * 0.20762050593046014f);
      float s;
      sincosf((float)h * theta, &s, &c);
      ssg = (l15 & 1) ? s : -s;
    }
    float* outp = Out + (size_t)sec * 33554432 + lc;
#pragma unroll
    for (int mi = 0; mi < 4; ++mi) {
      const f32x4 a = acc[mi][ni];
#pragma unroll
      for (int r = 0; r < 4; ++r) {
        const float val = a[r];
        float res = val;
        if (sec < 2) {
          const float other = __shfl_xor(val, 1);
          res = val * c + other * ssg;
        }
        __builtin_nontemporal_store(
            res, outp + (size_t)(m0 + wm + mi * 16 + lg * 4 + r) * 2048);
      }
    }
  }
}

extern "C" void kernel_launch(void* const* d_in, const int* in_sizes, int n_in,
                              void* d_out, int out_size, void* d_ws, size_t ws_size,
                              hipStream_t stream) {
  (void)in_sizes; (void)n_in; (void)out_size;
  const float* x  = (const float*)d_in[0];
  const float* Wq = (const float*)d_in[1];
  const float* Wk = (const float*)d_in[2];
  const float* Wv = (const float*)d_in[3];
  float* out = (float*)d_out;

  const size_t XB_ELEMS = 16384ull * 2048;
  const size_t WT_ELEMS = 6144ull * 2048;

  if (ws_size >= (XB_ELEMS + WT_ELEMS) * sizeof(unsigned short)) {
    unsigned short* Xb  = (unsigned short*)d_ws;
    unsigned short* WTf = Xb + XB_ELEMS;
    convert_x<<<2048, 256, 0, stream>>>(x, Xb, (int)(XB_ELEMS / 8));
    transpose_cvt3<<<dim3(32, 32, 3), 256, 0, stream>>>(Wq, Wk, Wv, WTf);
    hipError_t e = hipFuncSetAttribute(
        (const void*)qkv_fused17,
        hipFuncAttributeMaxDynamicSharedMemorySize, 163840);
    if (e == hipSuccess) {
      qkv_fused17<<<1536, 1024, 163840, stream>>>(Xb, WTf, out);
    } else {
      hipFuncSetAttribute((const void*)qkv_fused16,
                          hipFuncAttributeMaxDynamicSharedMemorySize, 131072);
      qkv_fused16<<<1536, 1024, 131072, stream>>>(Xb, WTf, out);
    }
  } else {
    // minimal fallback: should not happen for this problem size
    unsigned short* Xb = (unsigned short*)d_ws;
    convert_x<<<2048, 256, 0, stream>>>(x, Xb, (int)(XB_ELEMS / 8));
  }
}